// Round 4
// baseline (153.202 us; speedup 1.0000x reference)
//
#include <hip/hip_runtime.h>

// Cost volume, D=4: out[b,s,h,w] = mean_c feat1[b,c,h,w] * feat2[b,c,h,w+s-4]
// feat1/feat2: (8, 256, 96, 320) f32; out: (8, 9, 96, 320) f32.
// Latency-bound fix: depth-4 NAMED-register pipeline + sched_barrier fences
// + relaxed VGPR budget (__launch_bounds__ min-waves=3) so the backend cannot
// collapse the rotation to load-just-before-use (rounds 2/3 failure mode).

constexpr int B  = 8;
constexpr int C  = 256;
constexpr int H  = 96;
constexpr int W  = 320;
constexpr int NS = 9;            // 2*D+1 shifts
constexpr int QT = W / 4;        // 80 float4 per row
constexpr int RPB = 4;           // rows per block
constexpr int NTH = RPB * QT;    // 320 threads = 5 waves
constexpr int NC  = 4;           // channel chunks -> 768 blocks = 3/CU
constexpr int CCH = C / NC;      // 64 channels per chunk
constexpr int HW  = H * W;
constexpr int OUT_ELEMS = B * NS * H * W;   // 2,211,840

__global__ void zero_out_kernel(float* __restrict__ out, int n) {
    int i = blockIdx.x * blockDim.x + threadIdx.x;
    int stride = gridDim.x * blockDim.x;
    for (; i < n; i += stride) out[i] = 0.0f;
}

__global__ __launch_bounds__(NTH, 3)
void cv_kernel(const float* __restrict__ f1,
               const float* __restrict__ f2,
               float* __restrict__ part) {
    const int tid = threadIdx.x;
    const int q   = tid % QT;
    const int r   = tid / QT;

    const int blk    = blockIdx.x;
    const int cchunk = blk % NC;
    const int rowblk = blk / NC;
    const int hb     = rowblk % (H / RPB);
    const int b      = rowblk / (H / RPB);
    const int h      = hb * RPB + r;
    const int c0     = cchunk * CCH;

    const size_t off = ((size_t)(b * C + c0) * H + h) * (size_t)W + 4 * q;
    const float* p1 = f1 + off;
    const float* p2 = f2 + off;

    const bool has_lo = (q > 0);
    const bool has_hi = (q < QT - 1);
    const int  lo = has_lo ? -4 : 0;   // clamped address; zeroed on use
    const int  hi = has_hi ?  4 : 0;

    float acc[4][NS];
#pragma unroll
    for (int j = 0; j < 4; ++j)
#pragma unroll
        for (int s = 0; s < NS; ++s) acc[j][s] = 0.0f;

    // ---- depth-4 hand-rotated pipeline over NAMED registers ----
    float4 aA, x0A, x1A, x2A;
    float4 aB, x0B, x1B, x2B;
    float4 aC, x0C, x1C, x2C;
    float4 aD, x0D, x1D, x2D;

#define CV_LOAD(K)                                                \
    a##K  = *reinterpret_cast<const float4*>(p1);                 \
    x0##K = *reinterpret_cast<const float4*>(p2 + lo);            \
    x1##K = *reinterpret_cast<const float4*>(p2);                 \
    x2##K = *reinterpret_cast<const float4*>(p2 + hi);            \
    p1 += HW; p2 += HW;

#define CV_FMA(K) {                                               \
    float x[12] = { has_lo ? x0##K.x : 0.f, has_lo ? x0##K.y : 0.f, \
                    has_lo ? x0##K.z : 0.f, has_lo ? x0##K.w : 0.f, \
                    x1##K.x, x1##K.y, x1##K.z, x1##K.w,           \
                    has_hi ? x2##K.x : 0.f, has_hi ? x2##K.y : 0.f, \
                    has_hi ? x2##K.z : 0.f, has_hi ? x2##K.w : 0.f }; \
    float av[4] = {a##K.x, a##K.y, a##K.z, a##K.w};               \
    _Pragma("unroll")                                             \
    for (int j = 0; j < 4; ++j)                                   \
        _Pragma("unroll")                                         \
        for (int s = 0; s < NS; ++s)                              \
            acc[j][s] = fmaf(av[j], x[j + s], acc[j][s]); }

    // Prologue: channels 0..3 in flight.
    CV_LOAD(A) CV_LOAD(B) CV_LOAD(C) CV_LOAD(D)

    // Steady state: consume stage K (channel c+k), refill with channel c+4+k.
    // sched_barrier(0) after each phase: the scheduler cannot sink a stage's
    // loads toward their use 3 phases later -> >=12 loads (12 KB) in flight
    // per wave at all times. Waitcnt pass then emits counted vmcnt per use.
#pragma unroll 1
    for (int c = 0; c < CCH - 4; c += 4) {
        CV_FMA(A) CV_LOAD(A) __builtin_amdgcn_sched_barrier(0);
        CV_FMA(B) CV_LOAD(B) __builtin_amdgcn_sched_barrier(0);
        CV_FMA(C) CV_LOAD(C) __builtin_amdgcn_sched_barrier(0);
        CV_FMA(D) CV_LOAD(D) __builtin_amdgcn_sched_barrier(0);
    }
    // Epilogue: channels CCH-4 .. CCH-1 (loads already issued).
    CV_FMA(A) CV_FMA(B) CV_FMA(C) CV_FMA(D)

#undef CV_LOAD
#undef CV_FMA

    // Store partial sums: part[cchunk][b][s][h][w]
    float* basep = part + (size_t)cchunk * OUT_ELEMS;
#pragma unroll
    for (int s = 0; s < NS; ++s) {
        float4 v = make_float4(acc[0][s], acc[1][s], acc[2][s], acc[3][s]);
        *reinterpret_cast<float4*>(
            basep + ((size_t)(b * NS + s) * H + h) * (size_t)W + 4 * q) = v;
    }
}

// Fallback if ws is too small: simple atomic version (correctness only).
__global__ __launch_bounds__(NTH)
void cv_atomic_kernel(const float* __restrict__ f1,
                      const float* __restrict__ f2,
                      float* __restrict__ out) {
    const int tid = threadIdx.x;
    const int q = tid % QT, r = tid / QT;
    const int blk = blockIdx.x;
    const int cchunk = blk % NC;
    const int rowblk = blk / NC;
    const int hb = rowblk % (H / RPB);
    const int b  = rowblk / (H / RPB);
    const int h  = hb * RPB + r;
    const int c0 = cchunk * CCH;

    const size_t off = ((size_t)(b * C + c0) * H + h) * (size_t)W + 4 * q;
    const float* p1 = f1 + off;
    const float* p2 = f2 + off;
    const bool has_lo = (q > 0), has_hi = (q < QT - 1);
    const int lo = has_lo ? -4 : 0, hi = has_hi ? 4 : 0;

    float acc[4][NS];
#pragma unroll
    for (int j = 0; j < 4; ++j)
#pragma unroll
        for (int s = 0; s < NS; ++s) acc[j][s] = 0.0f;

    for (int c = 0; c < CCH; ++c) {
        float4 a  = *reinterpret_cast<const float4*>(p1);
        float4 x0 = *reinterpret_cast<const float4*>(p2 + lo);
        float4 x1 = *reinterpret_cast<const float4*>(p2);
        float4 x2 = *reinterpret_cast<const float4*>(p2 + hi);
        float x[12] = { has_lo ? x0.x : 0.f, has_lo ? x0.y : 0.f,
                        has_lo ? x0.z : 0.f, has_lo ? x0.w : 0.f,
                        x1.x, x1.y, x1.z, x1.w,
                        has_hi ? x2.x : 0.f, has_hi ? x2.y : 0.f,
                        has_hi ? x2.z : 0.f, has_hi ? x2.w : 0.f };
        float av[4] = {a.x, a.y, a.z, a.w};
#pragma unroll
        for (int j = 0; j < 4; ++j)
#pragma unroll
            for (int s = 0; s < NS; ++s)
                acc[j][s] = fmaf(av[j], x[j + s], acc[j][s]);
        p1 += HW; p2 += HW;
    }
    const float scale = 1.0f / (float)C;
#pragma unroll
    for (int s = 0; s < NS; ++s)
#pragma unroll
        for (int j = 0; j < 4; ++j)
            atomicAdd(out + ((size_t)(b * NS + s) * H + h) * (size_t)W + 4 * q + j,
                      acc[j][s] * scale);
}

__global__ void reduce_kernel(const float* __restrict__ part,
                              float* __restrict__ out, int n4) {
    const float scale = 1.0f / (float)C;
    const float4* p = reinterpret_cast<const float4*>(part);
    float4* o = reinterpret_cast<float4*>(out);
    int i = blockIdx.x * blockDim.x + threadIdx.x;
    int stride = gridDim.x * blockDim.x;
    const int n4e = OUT_ELEMS / 4;
    for (; i < n4; i += stride) {
        float4 v0 = p[i];
        float4 v1 = p[i + n4e];
        float4 v2 = p[i + 2 * n4e];
        float4 v3 = p[i + 3 * n4e];
        float4 rr;
        rr.x = (v0.x + v1.x + v2.x + v3.x) * scale;
        rr.y = (v0.y + v1.y + v2.y + v3.y) * scale;
        rr.z = (v0.z + v1.z + v2.z + v3.z) * scale;
        rr.w = (v0.w + v1.w + v2.w + v3.w) * scale;
        o[i] = rr;
    }
}

extern "C" void kernel_launch(void* const* d_in, const int* in_sizes, int n_in,
                              void* d_out, int out_size, void* d_ws, size_t ws_size,
                              hipStream_t stream) {
    const float* f1 = (const float*)d_in[0];
    const float* f2 = (const float*)d_in[1];
    float* out = (float*)d_out;

    dim3 grid(B * (H / RPB) * NC);   // 768 blocks
    dim3 block(NTH);                 // 320 threads

    const size_t need = (size_t)NC * OUT_ELEMS * sizeof(float);  // 35.4 MB
    if (ws_size >= need) {
        float* part = (float*)d_ws;
        hipLaunchKernelGGL(cv_kernel, grid, block, 0, stream, f1, f2, part);
        const int n4 = OUT_ELEMS / 4;   // 552,960
        hipLaunchKernelGGL(reduce_kernel, dim3(2160), dim3(256), 0, stream,
                           part, out, n4);
    } else {
        hipLaunchKernelGGL(zero_out_kernel, dim3(512), dim3(256), 0, stream,
                           out, out_size);
        hipLaunchKernelGGL(cv_atomic_kernel, grid, block, 0, stream, f1, f2, out);
    }
}

// Round 5
// 111.814 us; speedup vs baseline: 1.3701x; 1.3701x over previous
//
#include <hip/hip_runtime.h>

// Cost volume, D=4: out[b,s,h,w] = mean_c feat1[b,c,h,w] * feat2[b,c,h,w+s-4]
// feat1/feat2: (8, 256, 96, 320) f32; out: (8, 9, 96, 320) f32.
// R5: 2 global loads/iter (feat2 window served from padded LDS row, halo
// zeroed once -> no masks), 1-iteration register prefetch made structural:
// ds_write(cur) ; load(next) ; lgkmcnt(0) ; raw s_barrier (NO vmcnt drain) ;
// ds_read window ; FMA. Double-buffered LDS, one barrier per channel.

constexpr int B  = 8;
constexpr int C  = 256;
constexpr int H  = 96;
constexpr int W  = 320;
constexpr int NS = 9;            // 2*D+1 shifts
constexpr int QT = W / 4;        // 80 float4 per row
constexpr int RPB = 4;           // rows per block
constexpr int NTH = RPB * QT;    // 320 threads = 5 waves
constexpr int NC  = 4;           // channel chunks -> 768 blocks = 3/CU
constexpr int CCH = C / NC;      // 64 channels per chunk
constexpr int HW  = H * W;
constexpr int OUT_ELEMS = B * NS * H * W;   // 2,211,840
constexpr int PADW = W + 8;      // 4-float zero halo each side

__global__ void zero_out_kernel(float* __restrict__ out, int n) {
    int i = blockIdx.x * blockDim.x + threadIdx.x;
    int stride = gridDim.x * blockDim.x;
    for (; i < n; i += stride) out[i] = 0.0f;
}

__global__ __launch_bounds__(NTH, 4)
void cv_kernel(const float* __restrict__ f1,
               const float* __restrict__ f2,
               float* __restrict__ part) {
    __shared__ float bufA[RPB][PADW];
    __shared__ float bufB[RPB][PADW];

    const int tid = threadIdx.x;
    const int q   = tid % QT;
    const int r   = tid / QT;

    const int blk    = blockIdx.x;
    const int cchunk = blk % NC;
    const int rowblk = blk / NC;
    const int hb     = rowblk % (H / RPB);
    const int b      = rowblk / (H / RPB);
    const int h      = hb * RPB + r;
    const int c0     = cchunk * CCH;

    const size_t off = ((size_t)(b * C + c0) * H + h) * (size_t)W + 4 * q;
    const float* p1 = f1 + off;
    const float* p2 = f2 + off;

    // Zero the halo pads once; they are never rewritten. Covered by the
    // barrier inside the first STEP before any window read.
    if (q == 0) {
#pragma unroll
        for (int k = 0; k < 4; ++k) { bufA[r][k] = 0.f; bufB[r][k] = 0.f; }
    }
    if (q == QT - 1) {
#pragma unroll
        for (int k = 0; k < 4; ++k) {
            bufA[r][4 + W + k] = 0.f; bufB[r][4 + W + k] = 0.f;
        }
    }

    float acc[4][NS];
#pragma unroll
    for (int j = 0; j < 4; ++j)
#pragma unroll
        for (int s = 0; s < NS; ++s) acc[j][s] = 0.0f;

    // Prologue: channel 0 in registers.
    float4 a_cur = *reinterpret_cast<const float4*>(p1);
    float4 r_cur = *reinterpret_cast<const float4*>(p2);
    int cnext = 1;   // clamped to CCH-1 at the tail (dummy re-load, L1-hot)

    // One STEP per channel:
    //   ds_write cur feat2 row (auto vmcnt wait: its load issued a full
    //   iteration ago) -> issue next channel's 2 loads -> lgkmcnt(0) +
    //   raw s_barrier (prefetch loads stay in flight across it) ->
    //   unconditional 12-float window from padded LDS -> 36 FMAs.
#define STEP(BUF)                                                          \
    {                                                                      \
        *reinterpret_cast<float4*>(&BUF[r][4 + 4 * q]) = r_cur;            \
        const float4 a_nxt =                                               \
            *reinterpret_cast<const float4*>(p1 + (size_t)cnext * HW);     \
        const float4 r_nxt =                                               \
            *reinterpret_cast<const float4*>(p2 + (size_t)cnext * HW);     \
        cnext = (cnext < CCH - 1) ? cnext + 1 : cnext;                     \
        asm volatile("s_waitcnt lgkmcnt(0)" ::: "memory");                 \
        __builtin_amdgcn_s_barrier();                                      \
        asm volatile("" ::: "memory");                                     \
        const float4 x0 = *reinterpret_cast<const float4*>(&BUF[r][4 * q]);\
        const float4 x2 =                                                  \
            *reinterpret_cast<const float4*>(&BUF[r][4 * q + 8]);          \
        const float xw[12] = {x0.x,  x0.y,  x0.z,  x0.w,                   \
                              r_cur.x, r_cur.y, r_cur.z, r_cur.w,          \
                              x2.x,  x2.y,  x2.z,  x2.w};                  \
        const float av[4] = {a_cur.x, a_cur.y, a_cur.z, a_cur.w};          \
        _Pragma("unroll")                                                  \
        for (int j = 0; j < 4; ++j)                                        \
            _Pragma("unroll")                                              \
            for (int s = 0; s < NS; ++s)                                   \
                acc[j][s] = fmaf(av[j], xw[j + s], acc[j][s]);             \
        a_cur = a_nxt; r_cur = r_nxt;                                      \
    }

#pragma unroll 1
    for (int c = 0; c < CCH; c += 2) {
        STEP(bufA)
        STEP(bufB)
    }
#undef STEP

    // Store partial sums: part[cchunk][b][s][h][w]
    float* basep = part + (size_t)cchunk * OUT_ELEMS;
#pragma unroll
    for (int s = 0; s < NS; ++s) {
        float4 v = make_float4(acc[0][s], acc[1][s], acc[2][s], acc[3][s]);
        *reinterpret_cast<float4*>(
            basep + ((size_t)(b * NS + s) * H + h) * (size_t)W + 4 * q) = v;
    }
}

// Fallback if ws is too small: simple atomic version (correctness only).
__global__ __launch_bounds__(NTH)
void cv_atomic_kernel(const float* __restrict__ f1,
                      const float* __restrict__ f2,
                      float* __restrict__ out) {
    const int tid = threadIdx.x;
    const int q = tid % QT, r = tid / QT;
    const int blk = blockIdx.x;
    const int cchunk = blk % NC;
    const int rowblk = blk / NC;
    const int hb = rowblk % (H / RPB);
    const int b  = rowblk / (H / RPB);
    const int h  = hb * RPB + r;
    const int c0 = cchunk * CCH;

    const size_t off = ((size_t)(b * C + c0) * H + h) * (size_t)W + 4 * q;
    const float* p1 = f1 + off;
    const float* p2 = f2 + off;
    const bool has_lo = (q > 0), has_hi = (q < QT - 1);
    const int lo = has_lo ? -4 : 0, hi = has_hi ? 4 : 0;

    float acc[4][NS];
#pragma unroll
    for (int j = 0; j < 4; ++j)
#pragma unroll
        for (int s = 0; s < NS; ++s) acc[j][s] = 0.0f;

    for (int c = 0; c < CCH; ++c) {
        float4 a  = *reinterpret_cast<const float4*>(p1);
        float4 x0 = *reinterpret_cast<const float4*>(p2 + lo);
        float4 x1 = *reinterpret_cast<const float4*>(p2);
        float4 x2 = *reinterpret_cast<const float4*>(p2 + hi);
        float x[12] = { has_lo ? x0.x : 0.f, has_lo ? x0.y : 0.f,
                        has_lo ? x0.z : 0.f, has_lo ? x0.w : 0.f,
                        x1.x, x1.y, x1.z, x1.w,
                        has_hi ? x2.x : 0.f, has_hi ? x2.y : 0.f,
                        has_hi ? x2.z : 0.f, has_hi ? x2.w : 0.f };
        float av[4] = {a.x, a.y, a.z, a.w};
#pragma unroll
        for (int j = 0; j < 4; ++j)
#pragma unroll
            for (int s = 0; s < NS; ++s)
                acc[j][s] = fmaf(av[j], x[j + s], acc[j][s]);
        p1 += HW; p2 += HW;
    }
    const float scale = 1.0f / (float)C;
#pragma unroll
    for (int s = 0; s < NS; ++s)
#pragma unroll
        for (int j = 0; j < 4; ++j)
            atomicAdd(out + ((size_t)(b * NS + s) * H + h) * (size_t)W + 4 * q + j,
                      acc[j][s] * scale);
}

__global__ void reduce_kernel(const float* __restrict__ part,
                              float* __restrict__ out, int n4) {
    const float scale = 1.0f / (float)C;
    const float4* p = reinterpret_cast<const float4*>(part);
    float4* o = reinterpret_cast<float4*>(out);
    int i = blockIdx.x * blockDim.x + threadIdx.x;
    int stride = gridDim.x * blockDim.x;
    const int n4e = OUT_ELEMS / 4;
    for (; i < n4; i += stride) {
        float4 v0 = p[i];
        float4 v1 = p[i + n4e];
        float4 v2 = p[i + 2 * n4e];
        float4 v3 = p[i + 3 * n4e];
        float4 rr;
        rr.x = (v0.x + v1.x + v2.x + v3.x) * scale;
        rr.y = (v0.y + v1.y + v2.y + v3.y) * scale;
        rr.z = (v0.z + v1.z + v2.z + v3.z) * scale;
        rr.w = (v0.w + v1.w + v2.w + v3.w) * scale;
        o[i] = rr;
    }
}

extern "C" void kernel_launch(void* const* d_in, const int* in_sizes, int n_in,
                              void* d_out, int out_size, void* d_ws, size_t ws_size,
                              hipStream_t stream) {
    const float* f1 = (const float*)d_in[0];
    const float* f2 = (const float*)d_in[1];
    float* out = (float*)d_out;

    dim3 grid(B * (H / RPB) * NC);   // 768 blocks
    dim3 block(NTH);                 // 320 threads

    const size_t need = (size_t)NC * OUT_ELEMS * sizeof(float);  // 35.4 MB
    if (ws_size >= need) {
        float* part = (float*)d_ws;
        hipLaunchKernelGGL(cv_kernel, grid, block, 0, stream, f1, f2, part);
        const int n4 = OUT_ELEMS / 4;   // 552,960
        hipLaunchKernelGGL(reduce_kernel, dim3(2160), dim3(256), 0, stream,
                           part, out, n4);
    } else {
        hipLaunchKernelGGL(zero_out_kernel, dim3(512), dim3(256), 0, stream,
                           out, out_size);
        hipLaunchKernelGGL(cv_atomic_kernel, grid, block, 0, stream, f1, f2, out);
    }
}